// Round 1
// baseline (1062.064 us; speedup 1.0000x reference)
//
#include <hip/hip_runtime.h>

// SM-2 spaced-repetition scan: one thread per row, serial 400-step recurrence.
// Row = 400 contiguous f32 (1600 B). Memory-bound: ~839 MB streamed once.

constexpr int T = 400;          // MAX_SESSIONS
constexpr int F4_PER_ROW = T / 4;   // 100
constexpr int CHUNK_F4 = 4;         // 16 steps per chunk
constexpr int NCHUNK = F4_PER_ROW / CHUNK_F4;  // 25

__device__ __forceinline__ void sm2_step(float p, float& I, float& EF, float& n) {
    float q = p * 5.0f;
    bool correct = q >= 3.0f;
    bool brk = (p == -1.0f);
    // n==0 / n==1 / n>=2 partition; wrong answer resets interval to 1
    float In = (n >= 2.0f) ? (I * EF) : ((n == 1.0f) ? 6.0f : 1.0f);
    In = correct ? In : 1.0f;
    I = brk ? I : In;
    I = fminf(fmaxf(I, 1.0f), 274.0f);
    float d = 5.0f - q;
    float EFn = EF + (0.1f - d * (0.08f + d * 0.02f));
    EFn = fmaxf(EFn, 1.3f);
    EF = correct ? EFn : EF;
    n = correct ? (n + 1.0f) : 0.0f;
}

__global__ __launch_bounds__(256) void sm2_kernel(const float* __restrict__ hist,
                                                  float* __restrict__ out, int B) {
    int row = blockIdx.x * blockDim.x + threadIdx.x;
    if (row >= B) return;

    const float4* rowp = reinterpret_cast<const float4*>(hist + (size_t)row * T);

    float I = 1.0f, EF = 2.5f, n = 0.0f;

    float4 cur[CHUNK_F4], nxt[CHUNK_F4];
#pragma unroll
    for (int j = 0; j < CHUNK_F4; ++j) cur[j] = rowp[j];

#pragma unroll 1
    for (int c = 0; c < NCHUNK; ++c) {
        // prefetch next chunk (clamped index: last iter re-reads tail, L1-hit)
        int cn = (c + 1 < NCHUNK) ? (c + 1) : (NCHUNK - 1);
#pragma unroll
        for (int j = 0; j < CHUNK_F4; ++j) nxt[j] = rowp[cn * CHUNK_F4 + j];

#pragma unroll
        for (int j = 0; j < CHUNK_F4; ++j) {
            sm2_step(cur[j].x, I, EF, n);
            sm2_step(cur[j].y, I, EF, n);
            sm2_step(cur[j].z, I, EF, n);
            sm2_step(cur[j].w, I, EF, n);
        }

#pragma unroll
        for (int j = 0; j < CHUNK_F4; ++j) cur[j] = nxt[j];
    }

    // h_t = -I / log2(0.5) = I; final clip (no-op for I in [1,274], kept for fidelity)
    out[row] = fminf(fmaxf(I, 0.0001f), 274.0f);
}

extern "C" void kernel_launch(void* const* d_in, const int* in_sizes, int n_in,
                              void* d_out, int out_size, void* d_ws, size_t ws_size,
                              hipStream_t stream) {
    const float* hist = (const float*)d_in[0];
    float* out = (float*)d_out;
    int B = in_sizes[0] / T;   // 524288
    int threads = 256;
    int blocks = (B + threads - 1) / threads;
    sm2_kernel<<<blocks, threads, 0, stream>>>(hist, out, B);
}

// Round 3
// 1047.548 us; speedup vs baseline: 1.0139x; 1.0139x over previous
//
#include <hip/hip_runtime.h>

// SM-2 scan, LDS-staged coalesced version.
// Layout: hist[B][400] row-major f32. Block = 256 threads = 256 rows.
// 10 time-chunks x 40 steps: coalesced float4 global loads -> regs -> LDS
// (pad-41 row stride), then each thread consumes its own 40 steps serially.
// Reg-staged prefetch of chunk c+1 overlaps the serial compute of chunk c.

constexpr int T = 400;        // MAX_SESSIONS
constexpr int C = 40;         // time-steps per chunk
constexpr int NCH = T / C;    // 10 chunks
constexpr int F4 = C / 4;     // 10 float4 per row-chunk
constexpr int BLK = 256;
constexpr int PAD = 41;       // LDS row stride in floats (odd -> 2-way max aliasing)

__device__ __forceinline__ void sm2_step(float p, float& I, float& EF, float& n) {
    float q = p * 5.0f;
    bool correct = q >= 3.0f;
    bool brk = (p == -1.0f);
    float In = (n >= 2.0f) ? (I * EF) : ((n == 1.0f) ? 6.0f : 1.0f);
    In = correct ? In : 1.0f;
    I = brk ? I : In;
    I = fminf(fmaxf(I, 1.0f), 274.0f);
    float d = 5.0f - q;
    float EFn = EF + (0.1f - d * (0.08f + d * 0.02f));
    EFn = fmaxf(EFn, 1.3f);
    EF = correct ? EFn : EF;
    n = correct ? (n + 1.0f) : 0.0f;
}

__global__ __launch_bounds__(BLK) void sm2_kernel(const float* __restrict__ hist,
                                                  float* __restrict__ out, int B) {
    __shared__ float tile[BLK * PAD];   // 41984 B -> 3 blocks/CU

    const int t = threadIdx.x;
    const size_t base = (size_t)blockIdx.x * BLK;
    const float* gbase = hist + base * T;

    float I = 1.0f, EF = 2.5f, n = 0.0f;
    float4 stg[F4];

    // Per-thread tile coordinates for the cooperative load (constant across chunks).
    // f4-index f = i*BLK + t  ->  row r = f/F4, col4 c4 = f%F4.
    int roff[F4];   // element offset within a row-chunk region: r*T + c4*4
    int loff[F4];   // LDS offset: r*PAD + c4*4
#pragma unroll
    for (int i = 0; i < F4; ++i) {
        int f = i * BLK + t;
        int r = f / F4, c4 = f % F4;
        roff[i] = r * T + c4 * 4;
        loff[i] = r * PAD + c4 * 4;
    }

    // prologue: load chunk 0 (coalesced: consecutive lanes -> consecutive 16B)
#pragma unroll
    for (int i = 0; i < F4; ++i)
        stg[i] = *reinterpret_cast<const float4*>(gbase + roff[i]);

#pragma unroll 1
    for (int ch = 0; ch < NCH; ++ch) {
        // scatter staged regs to LDS
#pragma unroll
        for (int i = 0; i < F4; ++i) {
            float* p = &tile[loff[i]];
            p[0] = stg[i].x; p[1] = stg[i].y; p[2] = stg[i].z; p[3] = stg[i].w;
        }
        __syncthreads();

        // prefetch next chunk into regs; vmcnt waits land at next iteration's
        // LDS write, so the HBM latency hides under this chunk's compute.
        if (ch + 1 < NCH) {
            const float* gc = gbase + (ch + 1) * C;
#pragma unroll
            for (int i = 0; i < F4; ++i)
                stg[i] = *reinterpret_cast<const float4*>(gc + roff[i]);
        }

        // serial recurrence over this chunk from my private LDS row
        const float* myrow = &tile[t * PAD];
#pragma unroll
        for (int j = 0; j < C; ++j)
            sm2_step(myrow[j], I, EF, n);

        __syncthreads();
    }

    // h_t = -I / log2(0.5) = I; final clip
    out[base + t] = fminf(fmaxf(I, 0.0001f), 274.0f);
}

extern "C" void kernel_launch(void* const* d_in, const int* in_sizes, int n_in,
                              void* d_out, int out_size, void* d_ws, size_t ws_size,
                              hipStream_t stream) {
    const float* hist = (const float*)d_in[0];
    float* out = (float*)d_out;
    int B = in_sizes[0] / T;              // 524288
    int blocks = B / BLK;                 // 2048
    sm2_kernel<<<blocks, BLK, 0, stream>>>(hist, out, B);
}